// Round 9
// baseline (129.702 us; speedup 1.0000x reference)
//
#include <hip/hip_runtime.h>

// ---------------- problem constants ----------------
#define B_     16
#define L_     1024
#define D_     768
#define C_     500
#define J_     10
#define M_     (B_ * L_)        // 16384
#define NREAL  (C_ * J_)        // 5000
#define NPAD   5120             // 20 * 256
#define TM     256
#define TN     256
#define TK     64
#define KTILES (D_ / TK)        // 12

typedef __attribute__((ext_vector_type(8))) short short8;
typedef __attribute__((ext_vector_type(4))) float f32x4;

struct frag2 { short8 k[2]; };

// float <-> order-preserving uint (for atomicMax on signed floats)
static __device__ __forceinline__ unsigned f2ord(float f) {
    unsigned u = __float_as_uint(f);
    return (u & 0x80000000u) ? ~u : (u | 0x80000000u);
}
static __device__ __forceinline__ float ord2f(unsigned u) {
    return (u & 0x80000000u) ? __uint_as_float(u & 0x7fffffffu)
                             : __uint_as_float(~u);
}

// fp32 -> bf16 round-to-nearest-even
static __device__ __forceinline__ unsigned short f2bf(float f) {
    unsigned u = __float_as_uint(f);
    u += 0x7fffu + ((u >> 16) & 1u);
    return (unsigned short)(u >> 16);
}

// ---------------- kernel 1: prep = normalize both inputs + zero pooled ----------------
__global__ __launch_bounds__(256) void prep_kernel(
    const float* __restrict__ spatial, const float* __restrict__ protos,
    unsigned short* __restrict__ z, unsigned short* __restrict__ pbuf,
    unsigned int* __restrict__ pooled)
{
    const int bid = blockIdx.x;
    if (bid < 80) {
        uint4 zz = {0, 0, 0, 0};
        *(uint4*)(pooled + bid * 1024 + threadIdx.x * 4) = zz;
    }

    const float* in;
    unsigned short* out;
    int row, valid;
    if (bid < 4096) { in = spatial; out = z;    row = bid * 4 + (threadIdx.x >> 6);          valid = M_; }
    else            { in = protos;  out = pbuf; row = (bid - 4096) * 4 + (threadIdx.x >> 6); valid = NREAL; }
    const int lane = threadIdx.x & 63;

    unsigned short* orow = out + (size_t)row * D_;
    if (row >= valid) {                    // zero pad rows (protos only)
        ushort4 zz = {0, 0, 0, 0};
        #pragma unroll
        for (int p = 0; p < 3; ++p)
            *(ushort4*)(orow + (p * 64 + lane) * 4) = zz;
        return;
    }

    const float4* rp = (const float4*)(in + (size_t)row * D_);
    float4 v[3];
    float s = 0.f;
    #pragma unroll
    for (int p = 0; p < 3; ++p) {
        v[p] = rp[p * 64 + lane];
        s += v[p].x * v[p].x + v[p].y * v[p].y + v[p].z * v[p].z + v[p].w * v[p].w;
    }
    #pragma unroll
    for (int off = 32; off; off >>= 1) s += __shfl_xor(s, off);
    float inv = 1.f / fmaxf(sqrtf(s), 1e-12f);
    #pragma unroll
    for (int p = 0; p < 3; ++p) {
        ushort4 o;
        o.x = f2bf(v[p].x * inv);
        o.y = f2bf(v[p].y * inv);
        o.z = f2bf(v[p].z * inv);
        o.w = f2bf(v[p].w * inv);
        *(ushort4*)(orow + (p * 64 + lane) * 4) = o;
    }
}

// ---------------- kernel 2: 256x256 8-phase GEMM + fused max-over-L ----------------
// r8 schedule + one change: RD_B4 of the next K-tile moved from phase 3 to
// right after phase 2's VM+BAR (buf data sealed there) so its 8 ds_reads
// complete under MMPAIR(2)+MMPAIR(3) instead of stalling next MMPAIR(0).
// RD_A2(aO) stays in phase 3 to keep arch-VGPR live-set under 128.

#define MFMA(a, b, c) __builtin_amdgcn_mfma_f32_16x16x32_bf16(a, b, c, 0, 0, 0)
#define FENCE asm volatile("" ::: "memory")
#define BAR   do { FENCE; __builtin_amdgcn_s_barrier(); FENCE; } while (0)
#define VM(N) asm volatile("s_waitcnt vmcnt(" #N ")" ::: "memory")
#define PRIO1 __builtin_amdgcn_s_setprio(1)
#define PRIO0 __builtin_amdgcn_s_setprio(0)

// read a-frag pair (mi, mi+1), both kk, from buf p (offsets fold into ds imm)
#define RD_A2(dst, p, mi) do { \
    dst[0].k[0] = *(const short8*)(bA0 + (p)*32768 + (mi)*1024); \
    dst[0].k[1] = *(const short8*)(bA1 + (p)*32768 + (mi)*1024); \
    dst[1].k[0] = *(const short8*)(bA0 + (p)*32768 + ((mi)+1)*1024); \
    dst[1].k[1] = *(const short8*)(bA1 + (p)*32768 + ((mi)+1)*1024); \
} while (0)

// read all 4 b-frags, both kk, from buf p
#define RD_B4(dst, p) do { \
    _Pragma("unroll") \
    for (int ni_ = 0; ni_ < 4; ++ni_) { \
        dst[ni_].k[0] = *(const short8*)(bB0 + (p)*32768 + ni_*1024); \
        dst[ni_].k[1] = *(const short8*)(bB1 + (p)*32768 + ni_*1024); \
    } \
} while (0)

// stage one 8KB quarter (q) of A/B for buf p at k-offset k0 (elements)
#define STAGE_A(p, q, k0) __builtin_amdgcn_global_load_lds( \
    (const __attribute__((address_space(1))) void*)(Z + gA0 + (q)*64*D_ + (unsigned)(k0)), \
    (__attribute__((address_space(3))) void*)(lds + (p)*32768 + (q)*4096 + tid8), 16, 0, 0)
#define STAGE_B(p, q, k0) __builtin_amdgcn_global_load_lds( \
    (const __attribute__((address_space(1))) void*)(Pm + gB0 + (q)*64*D_ + (unsigned)(k0)), \
    (__attribute__((address_space(3))) void*)(lds + (p)*32768 + 16384 + (q)*4096 + tid8), 16, 0, 0)

// one 16-MFMA cluster: C rows 2j,2j+1 x ni 0..3 x kk 0,1
#define MMPAIR(j, S, Bv) do { \
    PRIO1; \
    _Pragma("unroll") \
    for (int ni_ = 0; ni_ < 4; ++ni_) { \
        acc[2*(j)][ni_]   = MFMA(S[0].k[0], Bv[ni_].k[0], acc[2*(j)][ni_]); \
        acc[2*(j)+1][ni_] = MFMA(S[1].k[0], Bv[ni_].k[0], acc[2*(j)+1][ni_]); \
        acc[2*(j)][ni_]   = MFMA(S[0].k[1], Bv[ni_].k[1], acc[2*(j)][ni_]); \
        acc[2*(j)+1][ni_] = MFMA(S[1].k[1], Bv[ni_].k[1], acc[2*(j)+1][ni_]); \
    } \
    PRIO0; \
} while (0)

__global__ __launch_bounds__(512, 1) void gemm_maxpool_kernel(
    const unsigned short* __restrict__ Z,   // [M_][D_] bf16 bits
    const unsigned short* __restrict__ Pm,  // [NPAD][D_] bf16 bits
    unsigned int* __restrict__ pooled)      // [B_][NPAD] ord-encoded max
{
    __shared__ unsigned short lds[65536];   // 128 KiB: buf{0,1} x (A 32K | B 32K)

    const int tid  = threadIdx.x;
    const int lane = tid & 63;
    const int wid  = tid >> 6;              // 0..7
    const int wm   = wid >> 2;              // 0..1
    const int wn   = wid & 3;               // 0..3

    // XCD L2-chunked mapping: XCD x owns bm in [8x, 8x+8), bn-outer/bm-inner
    const int xcd = (int)blockIdx.x & 7;
    const int idx = (int)blockIdx.x >> 3;   // 0..159
    const int bm  = xcd * 8 + (idx & 7);    // 0..63
    const int bn  = idx >> 3;               // 0..19
    const int row0 = bm * TM;
    const int col0 = bn * TN;

    // ---- staging addresses (T2 swizzle on global source, linear LDS dest) ----
    const int tr    = tid >> 3;                                   // row within quarter
    const int tswz  = ((tid & 7) * 16) ^ ((tr & 7) << 4);         // swizzled col byte
    const int tid8  = tid * 8;                                    // shorts (16B/thread)
    const unsigned gA0 = (unsigned)(row0 + tr) * D_ + (tswz >> 1);
    const unsigned gB0 = (unsigned)(col0 + tr) * D_ + (tswz >> 1);

    // ---- ds_read fragment base pointers (swizzled); reads add imm offsets ----
    const int l15   = lane & 15;
    const int swzl  = (lane & 7) << 4;
    const int colS0 = ((((lane >> 4) * 16)      ) ^ swzl) >> 1;
    const int colS1 = ((((lane >> 4) * 16) + 64 ) ^ swzl) >> 1;
    const unsigned short* bA0 = lds + (wm * 128 + l15) * 64 + colS0;
    const unsigned short* bA1 = lds + (wm * 128 + l15) * 64 + colS1;
    const unsigned short* bB0 = lds + 16384 + (wn * 64 + l15) * 64 + colS0;
    const unsigned short* bB1 = lds + 16384 + (wn * 64 + l15) * 64 + colS1;

    f32x4 acc[8][4] = {};
    frag2 aE[2], aO[2], bE[4], bO[4];

    // ---- prologue: stage tiles 0 (buf0) and 1 (buf1) ----
    STAGE_B(0,0,0);  STAGE_B(0,1,0);  STAGE_A(0,0,0);  STAGE_A(0,2,0);
    STAGE_B(0,2,0);  STAGE_B(0,3,0);  STAGE_A(0,1,0);  STAGE_A(0,3,0);
    STAGE_B(1,0,64); STAGE_B(1,1,64); STAGE_A(1,0,64); STAGE_A(1,2,64);
    STAGE_B(1,2,64); STAGE_B(1,3,64); STAGE_A(1,1,64); STAGE_A(1,3,64);
    VM(8);                      // tile0 landed; tile1 (8 loads) in flight
    BAR;
    RD_B4(bE, 0);               // tile0 B-all + a01
    RD_A2(aE, 0, 0);

    // ---- main loop: tiles 0..9, staging tiles 2..11 ----
    #pragma unroll 1
    for (int i = 0; i < 5; ++i) {
        const int kE = i * 128 + 128;   // k0 for tile 2i+2 (-> buf0)
        const int kO = i * 128 + 192;   // k0 for tile 2i+3 (-> buf1)
        frag2 t23[2], t45[2], t67[2];

        // ===== even tile (buf0): aE/bE =====
        RD_A2(t23, 0, 2);  STAGE_B(0, 0, kE);  STAGE_B(0, 1, kE);
        BAR; MMPAIR(0, aE, bE); BAR;

        RD_A2(t45, 0, 4);  STAGE_A(0, 0, kE);  STAGE_A(0, 2, kE);
        BAR; MMPAIR(1, t23, bE); BAR;

        RD_A2(t67, 0, 6);  STAGE_B(0, 2, kE);  STAGE_B(0, 3, kE);
        VM(6);                      // drain odd tile's 8 (buf1 sealed)
        BAR;
        RD_B4(bO, 1);               // early: hides under MMPAIR(2)+(3)
        MMPAIR(2, t45, bE); BAR;

        STAGE_A(0, 1, kE);  STAGE_A(0, 3, kE);
        MMPAIR(3, t67, bE);
        RD_A2(aO, 1, 0);            // 4 reads: short exposure into next MM0
        BAR;

        // ===== odd tile (buf1): aO/bO =====
        RD_A2(t23, 1, 2);  STAGE_B(1, 0, kO);  STAGE_B(1, 1, kO);
        BAR; MMPAIR(0, aO, bO); BAR;

        RD_A2(t45, 1, 4);  STAGE_A(1, 0, kO);  STAGE_A(1, 2, kO);
        BAR; MMPAIR(1, t23, bO); BAR;

        RD_A2(t67, 1, 6);  STAGE_B(1, 2, kO);  STAGE_B(1, 3, kO);
        VM(6);                      // drain even tile (2i+2)'s 8 (buf0 sealed)
        BAR;
        RD_B4(bE, 0);               // early
        MMPAIR(2, t45, bO); BAR;

        STAGE_A(1, 1, kO);  STAGE_A(1, 3, kO);
        MMPAIR(3, t67, bO);
        RD_A2(aE, 0, 0);
        BAR;
    }

    // ===== epilogue tile 10 (buf0), no staging =====
    {
        frag2 t23[2], t45[2], t67[2];
        RD_A2(t23, 0, 2);
        BAR; MMPAIR(0, aE, bE); BAR;
        RD_A2(t45, 0, 4);
        BAR; MMPAIR(1, t23, bE); BAR;
        RD_A2(t67, 0, 6);
        VM(0);                      // drain tile 11's 8 loads
        BAR;
        RD_B4(bO, 1);
        MMPAIR(2, t45, bE); BAR;
        MMPAIR(3, t67, bE);
        RD_A2(aO, 1, 0);
        BAR;

        // ===== epilogue tile 11 (buf1) =====
        RD_A2(t23, 1, 2);
        BAR; MMPAIR(0, aO, bO); BAR;
        RD_A2(t45, 1, 4);
        BAR; MMPAIR(1, t23, bO); BAR;
        RD_A2(t67, 1, 6);
        BAR; MMPAIR(2, t45, bO); BAR;
        MMPAIR(3, t67, bO);
    }

    // ---- fused max-pool epilogue ----
    // C/D layout: col = lane&15, row = (lane>>4)*4 + reg
    const int batch = row0 >> 10;           // 256 | 1024
    #pragma unroll
    for (int ni = 0; ni < 4; ++ni) {
        float v = -3.0e38f;
        #pragma unroll
        for (int mi = 0; mi < 8; ++mi)
            v = fmaxf(v, fmaxf(fmaxf(acc[mi][ni][0], acc[mi][ni][1]),
                               fmaxf(acc[mi][ni][2], acc[mi][ni][3])));
        v = fmaxf(v, __shfl_xor(v, 16));
        v = fmaxf(v, __shfl_xor(v, 32));
        if (lane < 16) {
            int col = col0 + wn * 64 + ni * 16 + lane;
            atomicMax(&pooled[(size_t)batch * NPAD + col], f2ord(v));
        }
    }
}

// ---------------- kernel 3: finalize logits ----------------
__global__ __launch_bounds__(256) void finalize_kernel(
    const unsigned int* __restrict__ pooled,  // [B_][NPAD]
    const float* __restrict__ rw,             // [C_][J_]
    const float* __restrict__ bias,           // [C_]
    float* __restrict__ out)                  // [B_][C_]
{
    int t = blockIdx.x * 256 + threadIdx.x;
    if (t >= B_ * C_) return;
    int b = t / C_, c = t % C_;
    float s = 0.f;
    #pragma unroll
    for (int j = 0; j < J_; ++j) {
        float pv = ord2f(pooled[(size_t)b * NPAD + c * J_ + j]);
        float x  = rw[c * J_ + j];
        float w  = fmaxf(x, 0.f) + log1pf(expf(-fabsf(x)));  // softplus
        s += pv * w;
    }
    out[t] = s + bias[c];
}

// ---------------- launch ----------------
extern "C" void kernel_launch(void* const* d_in, const int* in_sizes, int n_in,
                              void* d_out, int out_size, void* d_ws, size_t ws_size,
                              hipStream_t stream) {
    const float* spatial = (const float*)d_in[0];   // (16,1024,768)
    const float* protos  = (const float*)d_in[1];   // (500,10,768)
    const float* rw      = (const float*)d_in[2];   // (500,10)
    const float* bias    = (const float*)d_in[3];   // (500,)
    float* out = (float*)d_out;                     // (16,500)

    unsigned short* z = (unsigned short*)d_ws;                     // 16384*768 bf16
    unsigned short* p = z + (size_t)M_ * D_;                       // 5120*768 bf16
    unsigned int* pooled = (unsigned int*)(p + (size_t)NPAD * D_); // 16*5120 u32

    prep_kernel<<<M_ / 4 + NPAD / 4, 256, 0, stream>>>(spatial, protos, z, p, pooled);
    gemm_maxpool_kernel<<<(M_ / TM) * (NPAD / TN), 512, 0, stream>>>(z, p, pooled);
    finalize_kernel<<<(B_ * C_ + 255) / 256, 256, 0, stream>>>(pooled, rw, bias, out);
}

// Round 10
// 127.795 us; speedup vs baseline: 1.0149x; 1.0149x over previous
//
#include <hip/hip_runtime.h>

// ---------------- problem constants ----------------
#define B_     16
#define L_     1024
#define D_     768
#define C_     500
#define J_     10
#define M_     (B_ * L_)        // 16384
#define NREAL  (C_ * J_)        // 5000
#define NPAD   5120             // 20 * 256
#define TM     256
#define TN     256
#define TK     64
#define KTILES (D_ / TK)        // 12

typedef __attribute__((ext_vector_type(8))) short short8;
typedef __attribute__((ext_vector_type(4))) float f32x4;

struct frag2 { short8 k[2]; };

// float <-> order-preserving uint (for atomicMax on signed floats)
static __device__ __forceinline__ unsigned f2ord(float f) {
    unsigned u = __float_as_uint(f);
    return (u & 0x80000000u) ? ~u : (u | 0x80000000u);
}
static __device__ __forceinline__ float ord2f(unsigned u) {
    return (u & 0x80000000u) ? __uint_as_float(u & 0x7fffffffu)
                             : __uint_as_float(~u);
}

// fp32 -> bf16 round-to-nearest-even
static __device__ __forceinline__ unsigned short f2bf(float f) {
    unsigned u = __float_as_uint(f);
    u += 0x7fffu + ((u >> 16) & 1u);
    return (unsigned short)(u >> 16);
}

// ---------------- kernel 1: prep = normalize both inputs + zero pooled ----------------
__global__ __launch_bounds__(256) void prep_kernel(
    const float* __restrict__ spatial, const float* __restrict__ protos,
    unsigned short* __restrict__ z, unsigned short* __restrict__ pbuf,
    unsigned int* __restrict__ pooled)
{
    const int bid = blockIdx.x;
    if (bid < 80) {
        uint4 zz = {0, 0, 0, 0};
        *(uint4*)(pooled + bid * 1024 + threadIdx.x * 4) = zz;
    }

    const float* in;
    unsigned short* out;
    int row, valid;
    if (bid < 4096) { in = spatial; out = z;    row = bid * 4 + (threadIdx.x >> 6);          valid = M_; }
    else            { in = protos;  out = pbuf; row = (bid - 4096) * 4 + (threadIdx.x >> 6); valid = NREAL; }
    const int lane = threadIdx.x & 63;

    unsigned short* orow = out + (size_t)row * D_;
    if (row >= valid) {                    // zero pad rows (protos only)
        ushort4 zz = {0, 0, 0, 0};
        #pragma unroll
        for (int p = 0; p < 3; ++p)
            *(ushort4*)(orow + (p * 64 + lane) * 4) = zz;
        return;
    }

    const float4* rp = (const float4*)(in + (size_t)row * D_);
    float4 v[3];
    float s = 0.f;
    #pragma unroll
    for (int p = 0; p < 3; ++p) {
        v[p] = rp[p * 64 + lane];
        s += v[p].x * v[p].x + v[p].y * v[p].y + v[p].z * v[p].z + v[p].w * v[p].w;
    }
    #pragma unroll
    for (int off = 32; off; off >>= 1) s += __shfl_xor(s, off);
    float inv = 1.f / fmaxf(sqrtf(s), 1e-12f);
    #pragma unroll
    for (int p = 0; p < 3; ++p) {
        ushort4 o;
        o.x = f2bf(v[p].x * inv);
        o.y = f2bf(v[p].y * inv);
        o.z = f2bf(v[p].z * inv);
        o.w = f2bf(v[p].w * inv);
        *(ushort4*)(orow + (p * 64 + lane) * 4) = o;
    }
}

// ---------------- kernel 2: 256x256 merged-4-phase GEMM + fused max-over-L ----------
// R8 schedule with phase pairs merged: per K-tile 2 segments of
// {RD 8 ds_reads ; STAGE 4 ; BAR ; 32 MFMA ; BAR} -> 4 barrier pairs/K-tile
// instead of 8. bO/aO reads stay at segment end (R9 lesson: early bO = spill).
// VM(8) after all 8 of this tile's staging issues drains prev tile exactly.

#define MFMA(a, b, c) __builtin_amdgcn_mfma_f32_16x16x32_bf16(a, b, c, 0, 0, 0)
#define FENCE asm volatile("" ::: "memory")
#define BAR   do { FENCE; __builtin_amdgcn_s_barrier(); FENCE; } while (0)
#define VM(N) asm volatile("s_waitcnt vmcnt(" #N ")" ::: "memory")
#define PRIO1 __builtin_amdgcn_s_setprio(1)
#define PRIO0 __builtin_amdgcn_s_setprio(0)

// read a-frag pair (mi, mi+1), both kk, from buf p (offsets fold into ds imm)
#define RD_A2(dst, p, mi) do { \
    dst[0].k[0] = *(const short8*)(bA0 + (p)*32768 + (mi)*1024); \
    dst[0].k[1] = *(const short8*)(bA1 + (p)*32768 + (mi)*1024); \
    dst[1].k[0] = *(const short8*)(bA0 + (p)*32768 + ((mi)+1)*1024); \
    dst[1].k[1] = *(const short8*)(bA1 + (p)*32768 + ((mi)+1)*1024); \
} while (0)

// read all 4 b-frags, both kk, from buf p
#define RD_B4(dst, p) do { \
    _Pragma("unroll") \
    for (int ni_ = 0; ni_ < 4; ++ni_) { \
        dst[ni_].k[0] = *(const short8*)(bB0 + (p)*32768 + ni_*1024); \
        dst[ni_].k[1] = *(const short8*)(bB1 + (p)*32768 + ni_*1024); \
    } \
} while (0)

// stage one 8KB quarter (q) of A/B for buf p at k-offset k0 (elements)
#define STAGE_A(p, q, k0) __builtin_amdgcn_global_load_lds( \
    (const __attribute__((address_space(1))) void*)(Z + gA0 + (q)*64*D_ + (unsigned)(k0)), \
    (__attribute__((address_space(3))) void*)(lds + (p)*32768 + (q)*4096 + tid8), 16, 0, 0)
#define STAGE_B(p, q, k0) __builtin_amdgcn_global_load_lds( \
    (const __attribute__((address_space(1))) void*)(Pm + gB0 + (q)*64*D_ + (unsigned)(k0)), \
    (__attribute__((address_space(3))) void*)(lds + (p)*32768 + 16384 + (q)*4096 + tid8), 16, 0, 0)

// one 16-MFMA cluster: C rows 2j,2j+1 x ni 0..3 x kk 0,1
#define MMPAIR(j, S, Bv) do { \
    PRIO1; \
    _Pragma("unroll") \
    for (int ni_ = 0; ni_ < 4; ++ni_) { \
        acc[2*(j)][ni_]   = MFMA(S[0].k[0], Bv[ni_].k[0], acc[2*(j)][ni_]); \
        acc[2*(j)+1][ni_] = MFMA(S[1].k[0], Bv[ni_].k[0], acc[2*(j)+1][ni_]); \
        acc[2*(j)][ni_]   = MFMA(S[0].k[1], Bv[ni_].k[1], acc[2*(j)][ni_]); \
        acc[2*(j)+1][ni_] = MFMA(S[1].k[1], Bv[ni_].k[1], acc[2*(j)+1][ni_]); \
    } \
    PRIO0; \
} while (0)

__global__ __launch_bounds__(512, 1) void gemm_maxpool_kernel(
    const unsigned short* __restrict__ Z,   // [M_][D_] bf16 bits
    const unsigned short* __restrict__ Pm,  // [NPAD][D_] bf16 bits
    unsigned int* __restrict__ pooled)      // [B_][NPAD] ord-encoded max
{
    __shared__ unsigned short lds[65536];   // 128 KiB: buf{0,1} x (A 32K | B 32K)

    const int tid  = threadIdx.x;
    const int lane = tid & 63;
    const int wid  = tid >> 6;              // 0..7
    const int wm   = wid >> 2;              // 0..1
    const int wn   = wid & 3;               // 0..3

    // XCD L2-chunked mapping: XCD x owns bm in [8x, 8x+8), bn-outer/bm-inner
    const int xcd = (int)blockIdx.x & 7;
    const int idx = (int)blockIdx.x >> 3;   // 0..159
    const int bm  = xcd * 8 + (idx & 7);    // 0..63
    const int bn  = idx >> 3;               // 0..19
    const int row0 = bm * TM;
    const int col0 = bn * TN;

    // ---- staging addresses (T2 swizzle on global source, linear LDS dest) ----
    const int tr    = tid >> 3;                                   // row within quarter
    const int tswz  = ((tid & 7) * 16) ^ ((tr & 7) << 4);         // swizzled col byte
    const int tid8  = tid * 8;                                    // shorts (16B/thread)
    const unsigned gA0 = (unsigned)(row0 + tr) * D_ + (tswz >> 1);
    const unsigned gB0 = (unsigned)(col0 + tr) * D_ + (tswz >> 1);

    // ---- ds_read fragment base pointers (swizzled); reads add imm offsets ----
    const int l15   = lane & 15;
    const int swzl  = (lane & 7) << 4;
    const int colS0 = ((((lane >> 4) * 16)      ) ^ swzl) >> 1;
    const int colS1 = ((((lane >> 4) * 16) + 64 ) ^ swzl) >> 1;
    const unsigned short* bA0 = lds + (wm * 128 + l15) * 64 + colS0;
    const unsigned short* bA1 = lds + (wm * 128 + l15) * 64 + colS1;
    const unsigned short* bB0 = lds + 16384 + (wn * 64 + l15) * 64 + colS0;
    const unsigned short* bB1 = lds + 16384 + (wn * 64 + l15) * 64 + colS1;

    f32x4 acc[8][4] = {};
    frag2 aE[2], aO[2], bE[4], bO[4];

    // ---- prologue: stage tiles 0 (buf0) and 1 (buf1) ----
    STAGE_B(0,0,0);  STAGE_B(0,1,0);  STAGE_A(0,0,0);  STAGE_A(0,2,0);
    STAGE_B(0,2,0);  STAGE_B(0,3,0);  STAGE_A(0,1,0);  STAGE_A(0,3,0);
    STAGE_B(1,0,64); STAGE_B(1,1,64); STAGE_A(1,0,64); STAGE_A(1,2,64);
    STAGE_B(1,2,64); STAGE_B(1,3,64); STAGE_A(1,1,64); STAGE_A(1,3,64);
    VM(8);                      // tile0 landed; tile1 (8 loads) in flight
    BAR;
    RD_B4(bE, 0);               // tile0 B-all + a01
    RD_A2(aE, 0, 0);

    // ---- main loop: tiles 0..9, staging tiles 2..11 ----
    #pragma unroll 1
    for (int i = 0; i < 5; ++i) {
        const int kE = i * 128 + 128;   // k0 for tile 2i+2 (-> buf0)
        const int kO = i * 128 + 192;   // k0 for tile 2i+3 (-> buf1)
        frag2 t23[2], t45[2], t67[2];

        // ===== even tile (buf0): aE/bE =====
        RD_A2(t23, 0, 2);  RD_A2(t45, 0, 4);
        STAGE_B(0, 0, kE); STAGE_B(0, 1, kE); STAGE_A(0, 0, kE); STAGE_A(0, 2, kE);
        BAR; MMPAIR(0, aE, bE); MMPAIR(1, t23, bE); BAR;

        RD_A2(t67, 0, 6);
        STAGE_B(0, 2, kE); STAGE_B(0, 3, kE); STAGE_A(0, 1, kE); STAGE_A(0, 3, kE);
        VM(8);                      // drain odd tile's 8; tile 2i+2's 8 in flight
        BAR; MMPAIR(2, t45, bE); MMPAIR(3, t67, bE);
        RD_B4(bO, 1);  RD_A2(aO, 1, 0);
        BAR;

        // ===== odd tile (buf1): aO/bO =====
        RD_A2(t23, 1, 2);  RD_A2(t45, 1, 4);
        STAGE_B(1, 0, kO); STAGE_B(1, 1, kO); STAGE_A(1, 0, kO); STAGE_A(1, 2, kO);
        BAR; MMPAIR(0, aO, bO); MMPAIR(1, t23, bO); BAR;

        RD_A2(t67, 1, 6);
        STAGE_B(1, 2, kO); STAGE_B(1, 3, kO); STAGE_A(1, 1, kO); STAGE_A(1, 3, kO);
        VM(8);                      // drain even tile 2i+2's 8
        BAR; MMPAIR(2, t45, bO); MMPAIR(3, t67, bO);
        RD_B4(bE, 0);  RD_A2(aE, 0, 0);
        BAR;
    }

    // ===== epilogue tile 10 (buf0), no staging =====
    {
        frag2 t23[2], t45[2], t67[2];
        RD_A2(t23, 0, 2);  RD_A2(t45, 0, 4);
        BAR; MMPAIR(0, aE, bE); MMPAIR(1, t23, bE); BAR;

        RD_A2(t67, 0, 6);
        VM(0);                      // drain tile 11's 8 loads
        BAR; MMPAIR(2, t45, bE); MMPAIR(3, t67, bE);
        RD_B4(bO, 1);  RD_A2(aO, 1, 0);
        BAR;

        // ===== epilogue tile 11 (buf1) =====
        RD_A2(t23, 1, 2);  RD_A2(t45, 1, 4);
        BAR; MMPAIR(0, aO, bO); MMPAIR(1, t23, bO); BAR;

        RD_A2(t67, 1, 6);
        MMPAIR(2, t45, bO); MMPAIR(3, t67, bO);
    }

    // ---- fused max-pool epilogue ----
    // C/D layout: col = lane&15, row = (lane>>4)*4 + reg
    const int batch = row0 >> 10;           // 256 | 1024
    #pragma unroll
    for (int ni = 0; ni < 4; ++ni) {
        float v = -3.0e38f;
        #pragma unroll
        for (int mi = 0; mi < 8; ++mi)
            v = fmaxf(v, fmaxf(fmaxf(acc[mi][ni][0], acc[mi][ni][1]),
                               fmaxf(acc[mi][ni][2], acc[mi][ni][3])));
        v = fmaxf(v, __shfl_xor(v, 16));
        v = fmaxf(v, __shfl_xor(v, 32));
        if (lane < 16) {
            int col = col0 + wn * 64 + ni * 16 + lane;
            atomicMax(&pooled[(size_t)batch * NPAD + col], f2ord(v));
        }
    }
}

// ---------------- kernel 3: finalize logits ----------------
__global__ __launch_bounds__(256) void finalize_kernel(
    const unsigned int* __restrict__ pooled,  // [B_][NPAD]
    const float* __restrict__ rw,             // [C_][J_]
    const float* __restrict__ bias,           // [C_]
    float* __restrict__ out)                  // [B_][C_]
{
    int t = blockIdx.x * 256 + threadIdx.x;
    if (t >= B_ * C_) return;
    int b = t / C_, c = t % C_;
    float s = 0.f;
    #pragma unroll
    for (int j = 0; j < J_; ++j) {
        float pv = ord2f(pooled[(size_t)b * NPAD + c * J_ + j]);
        float x  = rw[c * J_ + j];
        float w  = fmaxf(x, 0.f) + log1pf(expf(-fabsf(x)));  // softplus
        s += pv * w;
    }
    out[t] = s + bias[c];
}

// ---------------- launch ----------------
extern "C" void kernel_launch(void* const* d_in, const int* in_sizes, int n_in,
                              void* d_out, int out_size, void* d_ws, size_t ws_size,
                              hipStream_t stream) {
    const float* spatial = (const float*)d_in[0];   // (16,1024,768)
    const float* protos  = (const float*)d_in[1];   // (500,10,768)
    const float* rw      = (const float*)d_in[2];   // (500,10)
    const float* bias    = (const float*)d_in[3];   // (500,)
    float* out = (float*)d_out;                     // (16,500)

    unsigned short* z = (unsigned short*)d_ws;                     // 16384*768 bf16
    unsigned short* p = z + (size_t)M_ * D_;                       // 5120*768 bf16
    unsigned int* pooled = (unsigned int*)(p + (size_t)NPAD * D_); // 16*5120 u32

    prep_kernel<<<M_ / 4 + NPAD / 4, 256, 0, stream>>>(spatial, protos, z, p, pooled);
    gemm_maxpool_kernel<<<(M_ / TM) * (NPAD / TN), 512, 0, stream>>>(z, p, pooled);
    finalize_kernel<<<(B_ * C_ + 255) / 256, 256, 0, stream>>>(pooled, rw, bias, out);
}

// Round 11
// 118.039 us; speedup vs baseline: 1.0988x; 1.0827x over previous
//
#include <hip/hip_runtime.h>

// ---------------- problem constants ----------------
#define B_     16
#define L_     1024
#define D_     768
#define C_     500
#define J_     10
#define M_     (B_ * L_)        // 16384
#define NREAL  (C_ * J_)        // 5000
#define NPAD   5120             // 20 * 256
#define TM     256
#define TN     256
#define TK     64
#define KTILES (D_ / TK)        // 12

typedef __attribute__((ext_vector_type(8))) short short8;
typedef __attribute__((ext_vector_type(4))) float f32x4;

struct frag2 { short8 k[2]; };

// float <-> order-preserving uint (for atomicMax on signed floats)
static __device__ __forceinline__ unsigned f2ord(float f) {
    unsigned u = __float_as_uint(f);
    return (u & 0x80000000u) ? ~u : (u | 0x80000000u);
}
static __device__ __forceinline__ float ord2f(unsigned u) {
    return (u & 0x80000000u) ? __uint_as_float(u & 0x7fffffffu)
                             : __uint_as_float(~u);
}

// fp32 -> bf16 round-to-nearest-even
static __device__ __forceinline__ unsigned short f2bf(float f) {
    unsigned u = __float_as_uint(f);
    u += 0x7fffu + ((u >> 16) & 1u);
    return (unsigned short)(u >> 16);
}

// ---------------- kernel 1: prep = normalize both inputs + zero pooled ----------------
__global__ __launch_bounds__(256) void prep_kernel(
    const float* __restrict__ spatial, const float* __restrict__ protos,
    unsigned short* __restrict__ z, unsigned short* __restrict__ pbuf,
    unsigned int* __restrict__ pooled)
{
    const int bid = blockIdx.x;
    if (bid < 80) {
        uint4 zz = {0, 0, 0, 0};
        *(uint4*)(pooled + bid * 1024 + threadIdx.x * 4) = zz;
    }

    const float* in;
    unsigned short* out;
    int row, valid;
    if (bid < 4096) { in = spatial; out = z;    row = bid * 4 + (threadIdx.x >> 6);          valid = M_; }
    else            { in = protos;  out = pbuf; row = (bid - 4096) * 4 + (threadIdx.x >> 6); valid = NREAL; }
    const int lane = threadIdx.x & 63;

    unsigned short* orow = out + (size_t)row * D_;
    if (row >= valid) {                    // zero pad rows (protos only)
        ushort4 zz = {0, 0, 0, 0};
        #pragma unroll
        for (int p = 0; p < 3; ++p)
            *(ushort4*)(orow + (p * 64 + lane) * 4) = zz;
        return;
    }

    const float4* rp = (const float4*)(in + (size_t)row * D_);
    float4 v[3];
    float s = 0.f;
    #pragma unroll
    for (int p = 0; p < 3; ++p) {
        v[p] = rp[p * 64 + lane];
        s += v[p].x * v[p].x + v[p].y * v[p].y + v[p].z * v[p].z + v[p].w * v[p].w;
    }
    #pragma unroll
    for (int off = 32; off; off >>= 1) s += __shfl_xor(s, off);
    float inv = 1.f / fmaxf(sqrtf(s), 1e-12f);
    #pragma unroll
    for (int p = 0; p < 3; ++p) {
        ushort4 o;
        o.x = f2bf(v[p].x * inv);
        o.y = f2bf(v[p].y * inv);
        o.z = f2bf(v[p].z * inv);
        o.w = f2bf(v[p].w * inv);
        *(ushort4*)(orow + (p * 64 + lane) * 4) = o;
    }
}

// ---------------- kernel 2: 256x256 8-phase GEMM + fused max-over-L ----------------
// R8 verified schedule (T2 swizzle + counted vmcnt + setprio, 16x16x32),
// 8 waves (2Mx4N), 128KiB LDS dbuf, 1280 blocks, XCD L2-chunked mapping.
// NOTE (R7/R9/R10 lessons): arch-VGPR budget is 128 (acc[8][4] owns the AGPR
// half); any schedule motion extending a 32-reg fragment's liveness spills.

#define MFMA(a, b, c) __builtin_amdgcn_mfma_f32_16x16x32_bf16(a, b, c, 0, 0, 0)
#define FENCE asm volatile("" ::: "memory")
#define BAR   do { FENCE; __builtin_amdgcn_s_barrier(); FENCE; } while (0)
#define VM(N) asm volatile("s_waitcnt vmcnt(" #N ")" ::: "memory")
#define PRIO1 __builtin_amdgcn_s_setprio(1)
#define PRIO0 __builtin_amdgcn_s_setprio(0)

// read a-frag pair (mi, mi+1), both kk, from buf p (offsets fold into ds imm)
#define RD_A2(dst, p, mi) do { \
    dst[0].k[0] = *(const short8*)(bA0 + (p)*32768 + (mi)*1024); \
    dst[0].k[1] = *(const short8*)(bA1 + (p)*32768 + (mi)*1024); \
    dst[1].k[0] = *(const short8*)(bA0 + (p)*32768 + ((mi)+1)*1024); \
    dst[1].k[1] = *(const short8*)(bA1 + (p)*32768 + ((mi)+1)*1024); \
} while (0)

// read all 4 b-frags, both kk, from buf p
#define RD_B4(dst, p) do { \
    _Pragma("unroll") \
    for (int ni_ = 0; ni_ < 4; ++ni_) { \
        dst[ni_].k[0] = *(const short8*)(bB0 + (p)*32768 + ni_*1024); \
        dst[ni_].k[1] = *(const short8*)(bB1 + (p)*32768 + ni_*1024); \
    } \
} while (0)

// stage one 8KB quarter (q) of A/B for buf p at k-offset k0 (elements)
#define STAGE_A(p, q, k0) __builtin_amdgcn_global_load_lds( \
    (const __attribute__((address_space(1))) void*)(Z + gA0 + (q)*64*D_ + (unsigned)(k0)), \
    (__attribute__((address_space(3))) void*)(lds + (p)*32768 + (q)*4096 + tid8), 16, 0, 0)
#define STAGE_B(p, q, k0) __builtin_amdgcn_global_load_lds( \
    (const __attribute__((address_space(1))) void*)(Pm + gB0 + (q)*64*D_ + (unsigned)(k0)), \
    (__attribute__((address_space(3))) void*)(lds + (p)*32768 + 16384 + (q)*4096 + tid8), 16, 0, 0)

// one 16-MFMA cluster: C rows 2j,2j+1 x ni 0..3 x kk 0,1
#define MMPAIR(j, S, Bv) do { \
    PRIO1; \
    _Pragma("unroll") \
    for (int ni_ = 0; ni_ < 4; ++ni_) { \
        acc[2*(j)][ni_]   = MFMA(S[0].k[0], Bv[ni_].k[0], acc[2*(j)][ni_]); \
        acc[2*(j)+1][ni_] = MFMA(S[1].k[0], Bv[ni_].k[0], acc[2*(j)+1][ni_]); \
        acc[2*(j)][ni_]   = MFMA(S[0].k[1], Bv[ni_].k[1], acc[2*(j)][ni_]); \
        acc[2*(j)+1][ni_] = MFMA(S[1].k[1], Bv[ni_].k[1], acc[2*(j)+1][ni_]); \
    } \
    PRIO0; \
} while (0)

__global__ __launch_bounds__(512, 1) void gemm_maxpool_kernel(
    const unsigned short* __restrict__ Z,   // [M_][D_] bf16 bits
    const unsigned short* __restrict__ Pm,  // [NPAD][D_] bf16 bits
    unsigned int* __restrict__ pooled)      // [B_][NPAD] ord-encoded max
{
    __shared__ unsigned short lds[65536];   // 128 KiB: buf{0,1} x (A 32K | B 32K)

    const int tid  = threadIdx.x;
    const int lane = tid & 63;
    const int wid  = tid >> 6;              // 0..7
    const int wm   = wid >> 2;              // 0..1
    const int wn   = wid & 3;               // 0..3

    // XCD L2-chunked mapping: XCD x owns bm in [8x, 8x+8), bn-outer/bm-inner
    const int xcd = (int)blockIdx.x & 7;
    const int idx = (int)blockIdx.x >> 3;   // 0..159
    const int bm  = xcd * 8 + (idx & 7);    // 0..63
    const int bn  = idx >> 3;               // 0..19
    const int row0 = bm * TM;
    const int col0 = bn * TN;

    // ---- staging addresses (T2 swizzle on global source, linear LDS dest) ----
    const int tr    = tid >> 3;                                   // row within quarter
    const int tswz  = ((tid & 7) * 16) ^ ((tr & 7) << 4);         // swizzled col byte
    const int tid8  = tid * 8;                                    // shorts (16B/thread)
    const unsigned gA0 = (unsigned)(row0 + tr) * D_ + (tswz >> 1);
    const unsigned gB0 = (unsigned)(col0 + tr) * D_ + (tswz >> 1);

    // ---- ds_read fragment base pointers (swizzled); reads add imm offsets ----
    const int l15   = lane & 15;
    const int swzl  = (lane & 7) << 4;
    const int colS0 = ((((lane >> 4) * 16)      ) ^ swzl) >> 1;
    const int colS1 = ((((lane >> 4) * 16) + 64 ) ^ swzl) >> 1;
    const unsigned short* bA0 = lds + (wm * 128 + l15) * 64 + colS0;
    const unsigned short* bA1 = lds + (wm * 128 + l15) * 64 + colS1;
    const unsigned short* bB0 = lds + 16384 + (wn * 64 + l15) * 64 + colS0;
    const unsigned short* bB1 = lds + 16384 + (wn * 64 + l15) * 64 + colS1;

    f32x4 acc[8][4] = {};
    frag2 aE[2], aO[2], bE[4], bO[4];

    // ---- prologue: stage tiles 0 (buf0) and 1 (buf1) ----
    STAGE_B(0,0,0);  STAGE_B(0,1,0);  STAGE_A(0,0,0);  STAGE_A(0,2,0);
    STAGE_B(0,2,0);  STAGE_B(0,3,0);  STAGE_A(0,1,0);  STAGE_A(0,3,0);
    STAGE_B(1,0,64); STAGE_B(1,1,64); STAGE_A(1,0,64); STAGE_A(1,2,64);
    STAGE_B(1,2,64); STAGE_B(1,3,64); STAGE_A(1,1,64); STAGE_A(1,3,64);
    VM(8);                      // tile0 landed; tile1 (8 loads) in flight
    BAR;
    RD_B4(bE, 0);               // tile0 B-all + a01
    RD_A2(aE, 0, 0);

    // ---- main loop: tiles 0..9, staging tiles 2..11 ----
    #pragma unroll 1
    for (int i = 0; i < 5; ++i) {
        const int kE = i * 128 + 128;   // k0 for tile 2i+2 (-> buf0)
        const int kO = i * 128 + 192;   // k0 for tile 2i+3 (-> buf1)
        frag2 t23[2], t45[2], t67[2];

        // ===== even tile (buf0): aE/bE =====
        RD_A2(t23, 0, 2);  STAGE_B(0, 0, kE);  STAGE_B(0, 1, kE);
        BAR; MMPAIR(0, aE, bE); BAR;

        RD_A2(t45, 0, 4);  STAGE_A(0, 0, kE);  STAGE_A(0, 2, kE);
        BAR; MMPAIR(1, t23, bE); BAR;

        RD_A2(t67, 0, 6);  STAGE_B(0, 2, kE);  STAGE_B(0, 3, kE);
        VM(6);                      // drain odd tile's 8; leave 6 in flight
        BAR; MMPAIR(2, t45, bE); BAR;

        STAGE_A(0, 1, kE);  STAGE_A(0, 3, kE);
        MMPAIR(3, t67, bE);
        RD_B4(bO, 1);  RD_A2(aO, 1, 0);         // next (odd) tile frags
        BAR;

        // ===== odd tile (buf1): aO/bO =====
        RD_A2(t23, 1, 2);  STAGE_B(1, 0, kO);  STAGE_B(1, 1, kO);
        BAR; MMPAIR(0, aO, bO); BAR;

        RD_A2(t45, 1, 4);  STAGE_A(1, 0, kO);  STAGE_A(1, 2, kO);
        BAR; MMPAIR(1, t23, bO); BAR;

        RD_A2(t67, 1, 6);  STAGE_B(1, 2, kO);  STAGE_B(1, 3, kO);
        VM(6);                      // drain even tile (2i+2)'s 8
        BAR; MMPAIR(2, t45, bO); BAR;

        STAGE_A(1, 1, kO);  STAGE_A(1, 3, kO);
        MMPAIR(3, t67, bO);
        RD_B4(bE, 0);  RD_A2(aE, 0, 0);         // tile 2i+2 frags
        BAR;
    }

    // ===== epilogue tile 10 (buf0), no staging =====
    {
        frag2 t23[2], t45[2], t67[2];
        RD_A2(t23, 0, 2);
        BAR; MMPAIR(0, aE, bE); BAR;
        RD_A2(t45, 0, 4);
        BAR; MMPAIR(1, t23, bE); BAR;
        RD_A2(t67, 0, 6);
        VM(0);                      // drain tile 11's 8 loads
        BAR; MMPAIR(2, t45, bE); BAR;
        MMPAIR(3, t67, bE);
        RD_B4(bO, 1);  RD_A2(aO, 1, 0);
        BAR;

        // ===== epilogue tile 11 (buf1) =====
        RD_A2(t23, 1, 2);
        BAR; MMPAIR(0, aO, bO); BAR;
        RD_A2(t45, 1, 4);
        BAR; MMPAIR(1, t23, bO); BAR;
        RD_A2(t67, 1, 6);
        BAR; MMPAIR(2, t45, bO); BAR;
        MMPAIR(3, t67, bO);
    }

    // ---- fused max-pool epilogue ----
    // C/D layout: col = lane&15, row = (lane>>4)*4 + reg
    const int batch = row0 >> 10;           // 256 | 1024
    #pragma unroll
    for (int ni = 0; ni < 4; ++ni) {
        float v = -3.0e38f;
        #pragma unroll
        for (int mi = 0; mi < 8; ++mi)
            v = fmaxf(v, fmaxf(fmaxf(acc[mi][ni][0], acc[mi][ni][1]),
                               fmaxf(acc[mi][ni][2], acc[mi][ni][3])));
        v = fmaxf(v, __shfl_xor(v, 16));
        v = fmaxf(v, __shfl_xor(v, 32));
        if (lane < 16) {
            int col = col0 + wn * 64 + ni * 16 + lane;
            atomicMax(&pooled[(size_t)batch * NPAD + col], f2ord(v));
        }
    }
}

// ---------------- kernel 3: finalize logits ----------------
__global__ __launch_bounds__(256) void finalize_kernel(
    const unsigned int* __restrict__ pooled,  // [B_][NPAD]
    const float* __restrict__ rw,             // [C_][J_]
    const float* __restrict__ bias,           // [C_]
    float* __restrict__ out)                  // [B_][C_]
{
    int t = blockIdx.x * 256 + threadIdx.x;
    if (t >= B_ * C_) return;
    int b = t / C_, c = t % C_;
    float s = 0.f;
    #pragma unroll
    for (int j = 0; j < J_; ++j) {
        float pv = ord2f(pooled[(size_t)b * NPAD + c * J_ + j]);
        float x  = rw[c * J_ + j];
        float w  = fmaxf(x, 0.f) + log1pf(expf(-fabsf(x)));  // softplus
        s += pv * w;
    }
    out[t] = s + bias[c];
}

// ---------------- launch ----------------
extern "C" void kernel_launch(void* const* d_in, const int* in_sizes, int n_in,
                              void* d_out, int out_size, void* d_ws, size_t ws_size,
                              hipStream_t stream) {
    const float* spatial = (const float*)d_in[0];   // (16,1024,768)
    const float* protos  = (const float*)d_in[1];   // (500,10,768)
    const float* rw      = (const float*)d_in[2];   // (500,10)
    const float* bias    = (const float*)d_in[3];   // (500,)
    float* out = (float*)d_out;                     // (16,500)

    unsigned short* z = (unsigned short*)d_ws;                     // 16384*768 bf16
    unsigned short* p = z + (size_t)M_ * D_;                       // 5120*768 bf16
    unsigned int* pooled = (unsigned int*)(p + (size_t)NPAD * D_); // 16*5120 u32

    prep_kernel<<<M_ / 4 + NPAD / 4, 256, 0, stream>>>(spatial, protos, z, p, pooled);
    gemm_maxpool_kernel<<<(M_ / TM) * (NPAD / TN), 512, 0, stream>>>(z, p, pooled);
    finalize_kernel<<<(B_ * C_ + 255) / 256, 256, 0, stream>>>(pooled, rw, bias, out);
}

// Round 12
// 116.257 us; speedup vs baseline: 1.1157x; 1.0153x over previous
//
#include <hip/hip_runtime.h>

// ---------------- problem constants ----------------
#define B_     16
#define L_     1024
#define D_     768
#define C_     500
#define J_     10
#define M_     (B_ * L_)        // 16384
#define NREAL  (C_ * J_)        // 5000
#define NPAD   5120             // 20 * 256
#define TM     256
#define TN     256
#define TK     64
#define KTILES (D_ / TK)        // 12

typedef __attribute__((ext_vector_type(8))) short short8;
typedef __attribute__((ext_vector_type(4))) float f32x4;

struct frag2 { short8 k[2]; };

// float <-> order-preserving uint (for atomicMax on signed floats)
static __device__ __forceinline__ unsigned f2ord(float f) {
    unsigned u = __float_as_uint(f);
    return (u & 0x80000000u) ? ~u : (u | 0x80000000u);
}
static __device__ __forceinline__ float ord2f(unsigned u) {
    return (u & 0x80000000u) ? __uint_as_float(u & 0x7fffffffu)
                             : __uint_as_float(~u);
}

// fp32 -> bf16 round-to-nearest-even
static __device__ __forceinline__ unsigned short f2bf(float f) {
    unsigned u = __float_as_uint(f);
    u += 0x7fffu + ((u >> 16) & 1u);
    return (unsigned short)(u >> 16);
}

// ---------------- kernel 1: prep = normalize both inputs + zero pooled ----------------
__global__ __launch_bounds__(256) void prep_kernel(
    const float* __restrict__ spatial, const float* __restrict__ protos,
    unsigned short* __restrict__ z, unsigned short* __restrict__ pbuf,
    unsigned int* __restrict__ pooled)
{
    const int bid = blockIdx.x;
    if (bid < 80) {
        uint4 zz = {0, 0, 0, 0};
        *(uint4*)(pooled + bid * 1024 + threadIdx.x * 4) = zz;
    }

    const float* in;
    unsigned short* out;
    int row, valid;
    if (bid < 4096) { in = spatial; out = z;    row = bid * 4 + (threadIdx.x >> 6);          valid = M_; }
    else            { in = protos;  out = pbuf; row = (bid - 4096) * 4 + (threadIdx.x >> 6); valid = NREAL; }
    const int lane = threadIdx.x & 63;

    unsigned short* orow = out + (size_t)row * D_;
    if (row >= valid) {                    // zero pad rows (protos only)
        ushort4 zz = {0, 0, 0, 0};
        #pragma unroll
        for (int p = 0; p < 3; ++p)
            *(ushort4*)(orow + (p * 64 + lane) * 4) = zz;
        return;
    }

    const float4* rp = (const float4*)(in + (size_t)row * D_);
    float4 v[3];
    float s = 0.f;
    #pragma unroll
    for (int p = 0; p < 3; ++p) {
        v[p] = rp[p * 64 + lane];
        s += v[p].x * v[p].x + v[p].y * v[p].y + v[p].z * v[p].z + v[p].w * v[p].w;
    }
    #pragma unroll
    for (int off = 32; off; off >>= 1) s += __shfl_xor(s, off);
    float inv = 1.f / fmaxf(sqrtf(s), 1e-12f);
    #pragma unroll
    for (int p = 0; p < 3; ++p) {
        ushort4 o;
        o.x = f2bf(v[p].x * inv);
        o.y = f2bf(v[p].y * inv);
        o.z = f2bf(v[p].z * inv);
        o.w = f2bf(v[p].w * inv);
        *(ushort4*)(orow + (p * 64 + lane) * 4) = o;
    }
}

// ---------------- kernel 2: 256x256 single-barrier-phase GEMM + fused max-over-L ----
// R8 schedule with ONE barrier per phase (8/K-tile-pair instead of 14).
// Staging is phase-shifted one slot so every LDS write keeps a >=2-barrier
// separation from the last read of its region (same margin class as R8):
//   writes of tile T+2: B q0q1 @P2, A q0q2 @P3, B q2q3 @P4, A q1q3 @next-P1.
// vmcnt: prologue VM(6) (tile0 drained, tile1's 6 in flight); every section
// P3 = VM(4) (drains the tile read at P4); epilogue-10 P3 = VM(0).
// Fragment lifetimes identical to R8 -> no added register pressure.

#define MFMA(a, b, c) __builtin_amdgcn_mfma_f32_16x16x32_bf16(a, b, c, 0, 0, 0)
#define FENCE asm volatile("" ::: "memory")
#define BAR   do { FENCE; __builtin_amdgcn_s_barrier(); FENCE; } while (0)
#define VM(N) asm volatile("s_waitcnt vmcnt(" #N ")" ::: "memory")
#define PRIO1 __builtin_amdgcn_s_setprio(1)
#define PRIO0 __builtin_amdgcn_s_setprio(0)

// read a-frag pair (mi, mi+1), both kk, from buf p (offsets fold into ds imm)
#define RD_A2(dst, p, mi) do { \
    dst[0].k[0] = *(const short8*)(bA0 + (p)*32768 + (mi)*1024); \
    dst[0].k[1] = *(const short8*)(bA1 + (p)*32768 + (mi)*1024); \
    dst[1].k[0] = *(const short8*)(bA0 + (p)*32768 + ((mi)+1)*1024); \
    dst[1].k[1] = *(const short8*)(bA1 + (p)*32768 + ((mi)+1)*1024); \
} while (0)

// read all 4 b-frags, both kk, from buf p
#define RD_B4(dst, p) do { \
    _Pragma("unroll") \
    for (int ni_ = 0; ni_ < 4; ++ni_) { \
        dst[ni_].k[0] = *(const short8*)(bB0 + (p)*32768 + ni_*1024); \
        dst[ni_].k[1] = *(const short8*)(bB1 + (p)*32768 + ni_*1024); \
    } \
} while (0)

// stage one 8KB quarter (q) of A/B for buf p at k-offset k0 (elements)
#define STAGE_A(p, q, k0) __builtin_amdgcn_global_load_lds( \
    (const __attribute__((address_space(1))) void*)(Z + gA0 + (q)*64*D_ + (unsigned)(k0)), \
    (__attribute__((address_space(3))) void*)(lds + (p)*32768 + (q)*4096 + tid8), 16, 0, 0)
#define STAGE_B(p, q, k0) __builtin_amdgcn_global_load_lds( \
    (const __attribute__((address_space(1))) void*)(Pm + gB0 + (q)*64*D_ + (unsigned)(k0)), \
    (__attribute__((address_space(3))) void*)(lds + (p)*32768 + 16384 + (q)*4096 + tid8), 16, 0, 0)

// one 16-MFMA cluster: C rows 2j,2j+1 x ni 0..3 x kk 0,1
#define MMPAIR(j, S, Bv) do { \
    PRIO1; \
    _Pragma("unroll") \
    for (int ni_ = 0; ni_ < 4; ++ni_) { \
        acc[2*(j)][ni_]   = MFMA(S[0].k[0], Bv[ni_].k[0], acc[2*(j)][ni_]); \
        acc[2*(j)+1][ni_] = MFMA(S[1].k[0], Bv[ni_].k[0], acc[2*(j)+1][ni_]); \
        acc[2*(j)][ni_]   = MFMA(S[0].k[1], Bv[ni_].k[1], acc[2*(j)][ni_]); \
        acc[2*(j)+1][ni_] = MFMA(S[1].k[1], Bv[ni_].k[1], acc[2*(j)+1][ni_]); \
    } \
    PRIO0; \
} while (0)

__global__ __launch_bounds__(512, 1) void gemm_maxpool_kernel(
    const unsigned short* __restrict__ Z,   // [M_][D_] bf16 bits
    const unsigned short* __restrict__ Pm,  // [NPAD][D_] bf16 bits
    unsigned int* __restrict__ pooled)      // [B_][NPAD] ord-encoded max
{
    __shared__ unsigned short lds[65536];   // 128 KiB: buf{0,1} x (A 32K | B 32K)

    const int tid  = threadIdx.x;
    const int lane = tid & 63;
    const int wid  = tid >> 6;              // 0..7
    const int wm   = wid >> 2;              // 0..1
    const int wn   = wid & 3;               // 0..3

    // XCD L2-chunked mapping: XCD x owns bm in [8x, 8x+8), bn-outer/bm-inner
    const int xcd = (int)blockIdx.x & 7;
    const int idx = (int)blockIdx.x >> 3;   // 0..159
    const int bm  = xcd * 8 + (idx & 7);    // 0..63
    const int bn  = idx >> 3;               // 0..19
    const int row0 = bm * TM;
    const int col0 = bn * TN;

    // ---- staging addresses (T2 swizzle on global source, linear LDS dest) ----
    const int tr    = tid >> 3;                                   // row within quarter
    const int tswz  = ((tid & 7) * 16) ^ ((tr & 7) << 4);         // swizzled col byte
    const int tid8  = tid * 8;                                    // shorts (16B/thread)
    const unsigned gA0 = (unsigned)(row0 + tr) * D_ + (tswz >> 1);
    const unsigned gB0 = (unsigned)(col0 + tr) * D_ + (tswz >> 1);

    // ---- ds_read fragment base pointers (swizzled); reads add imm offsets ----
    const int l15   = lane & 15;
    const int swzl  = (lane & 7) << 4;
    const int colS0 = ((((lane >> 4) * 16)      ) ^ swzl) >> 1;
    const int colS1 = ((((lane >> 4) * 16) + 64 ) ^ swzl) >> 1;
    const unsigned short* bA0 = lds + (wm * 128 + l15) * 64 + colS0;
    const unsigned short* bA1 = lds + (wm * 128 + l15) * 64 + colS1;
    const unsigned short* bB0 = lds + 16384 + (wn * 64 + l15) * 64 + colS0;
    const unsigned short* bB1 = lds + 16384 + (wn * 64 + l15) * 64 + colS1;

    f32x4 acc[8][4] = {};
    frag2 aE[2], aO[2], bE[4], bO[4];

    // ---- prologue: stage tile 0 (8 loads) + tile 1 first 6 ----
    STAGE_B(0,0,0);  STAGE_B(0,1,0);  STAGE_A(0,0,0);  STAGE_A(0,2,0);
    STAGE_B(0,2,0);  STAGE_B(0,3,0);  STAGE_A(0,1,0);  STAGE_A(0,3,0);
    STAGE_B(1,0,64); STAGE_B(1,1,64); STAGE_A(1,0,64); STAGE_A(1,2,64);
    STAGE_B(1,2,64); STAGE_B(1,3,64);
    VM(6);                      // tile0 landed; tile1's 6 in flight
    BAR;
    RD_B4(bE, 0);               // tile0 B-all + a01
    RD_A2(aE, 0, 0);

    // ---- main loop: tiles 0..9, staging (shifted) tiles 1..11 ----
    #pragma unroll 1
    for (int i = 0; i < 5; ++i) {
        const int kOp = i * 128 + 64;    // k0 of tile 2i+1 (buf1, last pair)
        const int kE  = i * 128 + 128;   // k0 of tile 2i+2 (buf0)
        const int kO  = i * 128 + 192;   // k0 of tile 2i+3 (buf1)
        frag2 t23[2], t45[2], t67[2];

        // ===== even tile (buf0): aE/bE =====
        RD_A2(t23, 0, 2);  STAGE_A(1, 1, kOp);  STAGE_A(1, 3, kOp);
        BAR; MMPAIR(0, aE, bE);

        RD_A2(t45, 0, 4);  STAGE_B(0, 0, kE);  STAGE_B(0, 1, kE);
        BAR; MMPAIR(1, t23, bE);

        RD_A2(t67, 0, 6);  STAGE_A(0, 0, kE);  STAGE_A(0, 2, kE);
        VM(4);                      // drain tile 2i+1; leave 4 in flight
        BAR; MMPAIR(2, t45, bE);

        STAGE_B(0, 2, kE);  STAGE_B(0, 3, kE);
        MMPAIR(3, t67, bE);
        RD_B4(bO, 1);  RD_A2(aO, 1, 0);         // tile 2i+1 frags
        BAR;

        // ===== odd tile (buf1): aO/bO =====
        RD_A2(t23, 1, 2);  STAGE_A(0, 1, kE);  STAGE_A(0, 3, kE);
        BAR; MMPAIR(0, aO, bO);

        RD_A2(t45, 1, 4);  STAGE_B(1, 0, kO);  STAGE_B(1, 1, kO);
        BAR; MMPAIR(1, t23, bO);

        RD_A2(t67, 1, 6);  STAGE_A(1, 0, kO);  STAGE_A(1, 2, kO);
        VM(4);                      // drain tile 2i+2; leave 4 in flight
        BAR; MMPAIR(2, t45, bO);

        STAGE_B(1, 2, kO);  STAGE_B(1, 3, kO);
        MMPAIR(3, t67, bO);
        RD_B4(bE, 0);  RD_A2(aE, 0, 0);         // tile 2i+2 frags
        BAR;
    }

    // ===== epilogue tile 10 (buf0): finish tile 11 staging (A q1,q3 @ k0=704) =====
    {
        frag2 t23[2], t45[2], t67[2];
        RD_A2(t23, 0, 2);  STAGE_A(1, 1, 704);  STAGE_A(1, 3, 704);
        BAR; MMPAIR(0, aE, bE);

        RD_A2(t45, 0, 4);
        BAR; MMPAIR(1, t23, bE);

        RD_A2(t67, 0, 6);
        VM(0);                      // drain tile 11's 8 loads
        BAR; MMPAIR(2, t45, bE);

        MMPAIR(3, t67, bE);
        RD_B4(bO, 1);  RD_A2(aO, 1, 0);
        BAR;

        // ===== epilogue tile 11 (buf1) =====
        RD_A2(t23, 1, 2);
        BAR; MMPAIR(0, aO, bO);

        RD_A2(t45, 1, 4);
        BAR; MMPAIR(1, t23, bO);

        RD_A2(t67, 1, 6);
        BAR; MMPAIR(2, t45, bO);

        MMPAIR(3, t67, bO);
    }

    // ---- fused max-pool epilogue ----
    // C/D layout: col = lane&15, row = (lane>>4)*4 + reg
    const int batch = row0 >> 10;           // 256 | 1024
    #pragma unroll
    for (int ni = 0; ni < 4; ++ni) {
        float v = -3.0e38f;
        #pragma unroll
        for (int mi = 0; mi < 8; ++mi)
            v = fmaxf(v, fmaxf(fmaxf(acc[mi][ni][0], acc[mi][ni][1]),
                               fmaxf(acc[mi][ni][2], acc[mi][ni][3])));
        v = fmaxf(v, __shfl_xor(v, 16));
        v = fmaxf(v, __shfl_xor(v, 32));
        if (lane < 16) {
            int col = col0 + wn * 64 + ni * 16 + lane;
            atomicMax(&pooled[(size_t)batch * NPAD + col], f2ord(v));
        }
    }
}

// ---------------- kernel 3: finalize logits ----------------
__global__ __launch_bounds__(256) void finalize_kernel(
    const unsigned int* __restrict__ pooled,  // [B_][NPAD]
    const float* __restrict__ rw,             // [C_][J_]
    const float* __restrict__ bias,           // [C_]
    float* __restrict__ out)                  // [B_][C_]
{
    int t = blockIdx.x * 256 + threadIdx.x;
    if (t >= B_ * C_) return;
    int b = t / C_, c = t % C_;
    float s = 0.f;
    #pragma unroll
    for (int j = 0; j < J_; ++j) {
        float pv = ord2f(pooled[(size_t)b * NPAD + c * J_ + j]);
        float x  = rw[c * J_ + j];
        float w  = fmaxf(x, 0.f) + log1pf(expf(-fabsf(x)));  // softplus
        s += pv * w;
    }
    out[t] = s + bias[c];
}

// ---------------- launch ----------------
extern "C" void kernel_launch(void* const* d_in, const int* in_sizes, int n_in,
                              void* d_out, int out_size, void* d_ws, size_t ws_size,
                              hipStream_t stream) {
    const float* spatial = (const float*)d_in[0];   // (16,1024,768)
    const float* protos  = (const float*)d_in[1];   // (500,10,768)
    const float* rw      = (const float*)d_in[2];   // (500,10)
    const float* bias    = (const float*)d_in[3];   // (500,)
    float* out = (float*)d_out;                     // (16,500)

    unsigned short* z = (unsigned short*)d_ws;                     // 16384*768 bf16
    unsigned short* p = z + (size_t)M_ * D_;                       // 5120*768 bf16
    unsigned int* pooled = (unsigned int*)(p + (size_t)NPAD * D_); // 16*5120 u32

    prep_kernel<<<M_ / 4 + NPAD / 4, 256, 0, stream>>>(spatial, protos, z, p, pooled);
    gemm_maxpool_kernel<<<(M_ / TM) * (NPAD / TN), 512, 0, stream>>>(z, p, pooled);
    finalize_kernel<<<(B_ * C_ + 255) / 256, 256, 0, stream>>>(pooled, rw, bias, out);
}

// Round 13
// 116.025 us; speedup vs baseline: 1.1179x; 1.0020x over previous
//
#include <hip/hip_runtime.h>

// ---------------- problem constants ----------------
#define B_     16
#define L_     1024
#define D_     768
#define C_     500
#define J_     10
#define M_     (B_ * L_)        // 16384
#define NREAL  (C_ * J_)        // 5000
#define NPAD   5120             // 20 * 256
#define TM     256
#define TN     256
#define TK     64
#define KTILES (D_ / TK)        // 12

typedef __attribute__((ext_vector_type(8))) short short8;
typedef __attribute__((ext_vector_type(4))) float f32x4;

struct frag2 { short8 k[2]; };

// float <-> order-preserving uint (for atomicMax on signed floats)
static __device__ __forceinline__ unsigned f2ord(float f) {
    unsigned u = __float_as_uint(f);
    return (u & 0x80000000u) ? ~u : (u | 0x80000000u);
}
static __device__ __forceinline__ float ord2f(unsigned u) {
    return (u & 0x80000000u) ? __uint_as_float(u & 0x7fffffffu)
                             : __uint_as_float(~u);
}

// fp32 -> bf16 round-to-nearest-even
static __device__ __forceinline__ unsigned short f2bf(float f) {
    unsigned u = __float_as_uint(f);
    u += 0x7fffu + ((u >> 16) & 1u);
    return (unsigned short)(u >> 16);
}

// ---------------- kernel 1: prep = normalize both inputs + zero pooled ----------------
__global__ __launch_bounds__(256) void prep_kernel(
    const float* __restrict__ spatial, const float* __restrict__ protos,
    unsigned short* __restrict__ z, unsigned short* __restrict__ pbuf,
    unsigned int* __restrict__ pooled)
{
    const int bid = blockIdx.x;
    if (bid < 80) {
        uint4 zz = {0, 0, 0, 0};
        *(uint4*)(pooled + bid * 1024 + threadIdx.x * 4) = zz;
    }

    const float* in;
    unsigned short* out;
    int row, valid;
    if (bid < 4096) { in = spatial; out = z;    row = bid * 4 + (threadIdx.x >> 6);          valid = M_; }
    else            { in = protos;  out = pbuf; row = (bid - 4096) * 4 + (threadIdx.x >> 6); valid = NREAL; }
    const int lane = threadIdx.x & 63;

    unsigned short* orow = out + (size_t)row * D_;
    if (row >= valid) {                    // zero pad rows (protos only)
        ushort4 zz = {0, 0, 0, 0};
        #pragma unroll
        for (int p = 0; p < 3; ++p)
            *(ushort4*)(orow + (p * 64 + lane) * 4) = zz;
        return;
    }

    const float4* rp = (const float4*)(in + (size_t)row * D_);
    float4 v[3];
    float s = 0.f;
    #pragma unroll
    for (int p = 0; p < 3; ++p) {
        v[p] = rp[p * 64 + lane];
        s += v[p].x * v[p].x + v[p].y * v[p].y + v[p].z * v[p].z + v[p].w * v[p].w;
    }
    #pragma unroll
    for (int off = 32; off; off >>= 1) s += __shfl_xor(s, off);
    float inv = 1.f / fmaxf(sqrtf(s), 1e-12f);
    #pragma unroll
    for (int p = 0; p < 3; ++p) {
        ushort4 o;
        o.x = f2bf(v[p].x * inv);
        o.y = f2bf(v[p].y * inv);
        o.z = f2bf(v[p].z * inv);
        o.w = f2bf(v[p].w * inv);
        *(ushort4*)(orow + (p * 64 + lane) * 4) = o;
    }
}

// ---------------- kernel 2: 256x256 two-barrier-per-K-tile GEMM + fused max-over-L ----
// R12 schedule with only 2 barriers per K-tile: mid-BAR (after VM(4), seals
// the tile read at section end) + end-BAR (after next-tile frag reads).
// Read/consume order identical to R12 -> identical register liveness.
// Staging slot order per section: [prev-tile A q1q3][cur+2 A q0q2][cur+2 B
// q0q1] then VM(4) drains the 8 oldest (= tile read at section end exactly),
// [B q2q3] after mid-BAR. Write-vs-read margins: >=2 barriers or >=550-cyc
// issue distance (ds_read services ~150cy; gload_lds write lands ~400+cy).

#define MFMA(a, b, c) __builtin_amdgcn_mfma_f32_16x16x32_bf16(a, b, c, 0, 0, 0)
#define FENCE asm volatile("" ::: "memory")
#define BAR   do { FENCE; __builtin_amdgcn_s_barrier(); FENCE; } while (0)
#define VM(N) asm volatile("s_waitcnt vmcnt(" #N ")" ::: "memory")
#define PRIO1 __builtin_amdgcn_s_setprio(1)
#define PRIO0 __builtin_amdgcn_s_setprio(0)

// read a-frag pair (mi, mi+1), both kk, from buf p (offsets fold into ds imm)
#define RD_A2(dst, p, mi) do { \
    dst[0].k[0] = *(const short8*)(bA0 + (p)*32768 + (mi)*1024); \
    dst[0].k[1] = *(const short8*)(bA1 + (p)*32768 + (mi)*1024); \
    dst[1].k[0] = *(const short8*)(bA0 + (p)*32768 + ((mi)+1)*1024); \
    dst[1].k[1] = *(const short8*)(bA1 + (p)*32768 + ((mi)+1)*1024); \
} while (0)

// read all 4 b-frags, both kk, from buf p
#define RD_B4(dst, p) do { \
    _Pragma("unroll") \
    for (int ni_ = 0; ni_ < 4; ++ni_) { \
        dst[ni_].k[0] = *(const short8*)(bB0 + (p)*32768 + ni_*1024); \
        dst[ni_].k[1] = *(const short8*)(bB1 + (p)*32768 + ni_*1024); \
    } \
} while (0)

// stage one 8KB quarter (q) of A/B for buf p at k-offset k0 (elements)
#define STAGE_A(p, q, k0) __builtin_amdgcn_global_load_lds( \
    (const __attribute__((address_space(1))) void*)(Z + gA0 + (q)*64*D_ + (unsigned)(k0)), \
    (__attribute__((address_space(3))) void*)(lds + (p)*32768 + (q)*4096 + tid8), 16, 0, 0)
#define STAGE_B(p, q, k0) __builtin_amdgcn_global_load_lds( \
    (const __attribute__((address_space(1))) void*)(Pm + gB0 + (q)*64*D_ + (unsigned)(k0)), \
    (__attribute__((address_space(3))) void*)(lds + (p)*32768 + 16384 + (q)*4096 + tid8), 16, 0, 0)

// one 16-MFMA cluster: C rows 2j,2j+1 x ni 0..3 x kk 0,1
#define MMPAIR(j, S, Bv) do { \
    PRIO1; \
    _Pragma("unroll") \
    for (int ni_ = 0; ni_ < 4; ++ni_) { \
        acc[2*(j)][ni_]   = MFMA(S[0].k[0], Bv[ni_].k[0], acc[2*(j)][ni_]); \
        acc[2*(j)+1][ni_] = MFMA(S[1].k[0], Bv[ni_].k[0], acc[2*(j)+1][ni_]); \
        acc[2*(j)][ni_]   = MFMA(S[0].k[1], Bv[ni_].k[1], acc[2*(j)][ni_]); \
        acc[2*(j)+1][ni_] = MFMA(S[1].k[1], Bv[ni_].k[1], acc[2*(j)+1][ni_]); \
    } \
    PRIO0; \
} while (0)

__global__ __launch_bounds__(512, 1) void gemm_maxpool_kernel(
    const unsigned short* __restrict__ Z,   // [M_][D_] bf16 bits
    const unsigned short* __restrict__ Pm,  // [NPAD][D_] bf16 bits
    unsigned int* __restrict__ pooled)      // [B_][NPAD] ord-encoded max
{
    __shared__ unsigned short lds[65536];   // 128 KiB: buf{0,1} x (A 32K | B 32K)

    const int tid  = threadIdx.x;
    const int lane = tid & 63;
    const int wid  = tid >> 6;              // 0..7
    const int wm   = wid >> 2;              // 0..1
    const int wn   = wid & 3;               // 0..3

    // XCD L2-chunked mapping: XCD x owns bm in [8x, 8x+8), bn-outer/bm-inner
    const int xcd = (int)blockIdx.x & 7;
    const int idx = (int)blockIdx.x >> 3;   // 0..159
    const int bm  = xcd * 8 + (idx & 7);    // 0..63
    const int bn  = idx >> 3;               // 0..19
    const int row0 = bm * TM;
    const int col0 = bn * TN;

    // ---- staging addresses (T2 swizzle on global source, linear LDS dest) ----
    const int tr    = tid >> 3;                                   // row within quarter
    const int tswz  = ((tid & 7) * 16) ^ ((tr & 7) << 4);         // swizzled col byte
    const int tid8  = tid * 8;                                    // shorts (16B/thread)
    const unsigned gA0 = (unsigned)(row0 + tr) * D_ + (tswz >> 1);
    const unsigned gB0 = (unsigned)(col0 + tr) * D_ + (tswz >> 1);

    // ---- ds_read fragment base pointers (swizzled); reads add imm offsets ----
    const int l15   = lane & 15;
    const int swzl  = (lane & 7) << 4;
    const int colS0 = ((((lane >> 4) * 16)      ) ^ swzl) >> 1;
    const int colS1 = ((((lane >> 4) * 16) + 64 ) ^ swzl) >> 1;
    const unsigned short* bA0 = lds + (wm * 128 + l15) * 64 + colS0;
    const unsigned short* bA1 = lds + (wm * 128 + l15) * 64 + colS1;
    const unsigned short* bB0 = lds + 16384 + (wn * 64 + l15) * 64 + colS0;
    const unsigned short* bB1 = lds + 16384 + (wn * 64 + l15) * 64 + colS1;

    f32x4 acc[8][4] = {};
    frag2 aE[2], aO[2], bE[4], bO[4];

    // ---- prologue: stage tile 0 (8 loads) + tile 1 first 6 ----
    STAGE_B(0,0,0);  STAGE_B(0,1,0);  STAGE_A(0,0,0);  STAGE_A(0,2,0);
    STAGE_B(0,2,0);  STAGE_B(0,3,0);  STAGE_A(0,1,0);  STAGE_A(0,3,0);
    STAGE_B(1,0,64); STAGE_B(1,1,64); STAGE_A(1,0,64); STAGE_A(1,2,64);
    STAGE_B(1,2,64); STAGE_B(1,3,64);
    VM(6);                      // tile0 landed; tile1's 6 in flight
    BAR;
    RD_B4(bE, 0);               // tile0 B-all + a01
    RD_A2(aE, 0, 0);

    // ---- main loop: tiles 0..9, staging (shifted) tiles 1..11 ----
    #pragma unroll 1
    for (int i = 0; i < 5; ++i) {
        const int kOp = i * 128 + 64;    // k0 of tile 2i+1 (buf1, last pair)
        const int kE  = i * 128 + 128;   // k0 of tile 2i+2 (buf0)
        const int kO  = i * 128 + 192;   // k0 of tile 2i+3 (buf1)
        frag2 t23[2], t45[2], t67[2];

        // ===== even tile (buf0): aE/bE =====
        RD_A2(t23, 0, 2);
        STAGE_A(1, 1, kOp);  STAGE_A(1, 3, kOp);    // tile 2i+1 last 2 (oldest)
        MMPAIR(0, aE, bE);
        RD_A2(t45, 0, 4);
        STAGE_A(0, 0, kE);   STAGE_A(0, 2, kE);     // tile 2i+2 A q0,q2
        MMPAIR(1, t23, bE);
        RD_A2(t67, 0, 6);
        STAGE_B(0, 0, kE);   STAGE_B(0, 1, kE);     // tile 2i+2 B q0,q1
        VM(4);                      // drain tile 2i+1's 8; leave 4 in flight
        BAR;
        MMPAIR(2, t45, bE);
        STAGE_B(0, 2, kE);   STAGE_B(0, 3, kE);     // tile 2i+2 B q2,q3
        MMPAIR(3, t67, bE);
        RD_B4(bO, 1);  RD_A2(aO, 1, 0);             // tile 2i+1 frags
        BAR;

        // ===== odd tile (buf1): aO/bO =====
        RD_A2(t23, 1, 2);
        STAGE_A(0, 1, kE);   STAGE_A(0, 3, kE);     // tile 2i+2 last 2 (oldest)
        MMPAIR(0, aO, bO);
        RD_A2(t45, 1, 4);
        STAGE_A(1, 0, kO);   STAGE_A(1, 2, kO);     // tile 2i+3 A q0,q2
        MMPAIR(1, t23, bO);
        RD_A2(t67, 1, 6);
        STAGE_B(1, 0, kO);   STAGE_B(1, 1, kO);     // tile 2i+3 B q0,q1
        VM(4);                      // drain tile 2i+2's 8; leave 4 in flight
        BAR;
        MMPAIR(2, t45, bO);
        STAGE_B(1, 2, kO);   STAGE_B(1, 3, kO);     // tile 2i+3 B q2,q3
        MMPAIR(3, t67, bO);
        RD_B4(bE, 0);  RD_A2(aE, 0, 0);             // tile 2i+2 frags
        BAR;
    }

    // ===== epilogue tile 10 (buf0): finish tile 11 staging (A q1,q3 @ k0=704) =====
    {
        frag2 t23[2], t45[2], t67[2];
        RD_A2(t23, 0, 2);
        STAGE_A(1, 1, 704);  STAGE_A(1, 3, 704);
        MMPAIR(0, aE, bE);
        RD_A2(t45, 0, 4);
        MMPAIR(1, t23, bE);
        RD_A2(t67, 0, 6);
        VM(0);                      // drain tile 11's 8 loads
        BAR;
        MMPAIR(2, t45, bE);
        MMPAIR(3, t67, bE);
        RD_B4(bO, 1);  RD_A2(aO, 1, 0);
        BAR;

        // ===== epilogue tile 11 (buf1): no writes remain -> no barriers =====
        RD_A2(t23, 1, 2);
        MMPAIR(0, aO, bO);
        RD_A2(t45, 1, 4);
        MMPAIR(1, t23, bO);
        RD_A2(t67, 1, 6);
        MMPAIR(2, t45, bO);
        MMPAIR(3, t67, bO);
    }

    // ---- fused max-pool epilogue ----
    // C/D layout: col = lane&15, row = (lane>>4)*4 + reg
    const int batch = row0 >> 10;           // 256 | 1024
    #pragma unroll
    for (int ni = 0; ni < 4; ++ni) {
        float v = -3.0e38f;
        #pragma unroll
        for (int mi = 0; mi < 8; ++mi)
            v = fmaxf(v, fmaxf(fmaxf(acc[mi][ni][0], acc[mi][ni][1]),
                               fmaxf(acc[mi][ni][2], acc[mi][ni][3])));
        v = fmaxf(v, __shfl_xor(v, 16));
        v = fmaxf(v, __shfl_xor(v, 32));
        if (lane < 16) {
            int col = col0 + wn * 64 + ni * 16 + lane;
            atomicMax(&pooled[(size_t)batch * NPAD + col], f2ord(v));
        }
    }
}

// ---------------- kernel 3: finalize logits ----------------
__global__ __launch_bounds__(256) void finalize_kernel(
    const unsigned int* __restrict__ pooled,  // [B_][NPAD]
    const float* __restrict__ rw,             // [C_][J_]
    const float* __restrict__ bias,           // [C_]
    float* __restrict__ out)                  // [B_][C_]
{
    int t = blockIdx.x * 256 + threadIdx.x;
    if (t >= B_ * C_) return;
    int b = t / C_, c = t % C_;
    float s = 0.f;
    #pragma unroll
    for (int j = 0; j < J_; ++j) {
        float pv = ord2f(pooled[(size_t)b * NPAD + c * J_ + j]);
        float x  = rw[c * J_ + j];
        float w  = fmaxf(x, 0.f) + log1pf(expf(-fabsf(x)));  // softplus
        s += pv * w;
    }
    out[t] = s + bias[c];
}

// ---------------- launch ----------------
extern "C" void kernel_launch(void* const* d_in, const int* in_sizes, int n_in,
                              void* d_out, int out_size, void* d_ws, size_t ws_size,
                              hipStream_t stream) {
    const float* spatial = (const float*)d_in[0];   // (16,1024,768)
    const float* protos  = (const float*)d_in[1];   // (500,10,768)
    const float* rw      = (const float*)d_in[2];   // (500,10)
    const float* bias    = (const float*)d_in[3];   // (500,)
    float* out = (float*)d_out;                     // (16,500)

    unsigned short* z = (unsigned short*)d_ws;                     // 16384*768 bf16
    unsigned short* p = z + (size_t)M_ * D_;                       // 5120*768 bf16
    unsigned int* pooled = (unsigned int*)(p + (size_t)NPAD * D_); // 16*5120 u32

    prep_kernel<<<M_ / 4 + NPAD / 4, 256, 0, stream>>>(spatial, protos, z, p, pooled);
    gemm_maxpool_kernel<<<(M_ / TM) * (NPAD / TN), 512, 0, stream>>>(z, p, pooled);
    finalize_kernel<<<(B_ * C_ + 255) / 256, 256, 0, stream>>>(pooled, rw, bias, out);
}